// Round 1
// baseline (703.858 us; speedup 1.0000x reference)
//
#include <hip/hip_runtime.h>
#include <hip/hip_bf16.h>
#include <cstdint>
#include <cstddef>

typedef __bf16 bf16_t;
typedef __attribute__((ext_vector_type(8))) __bf16 bf16x8;
typedef __attribute__((ext_vector_type(4))) float f32x4;

#define B_ 2
#define T_ 2048
#define DIM_ 2048
#define H_ 16
#define DH_ 128
#define DD_ 64
#define DQK_ 192              // DH_ + DD_
#define QSTRIDE_ 3072         // H_ * DQK_
#define BT_ 4096              // B_ * T_

__device__ __forceinline__ void gload16(const void* g, void* lds) {
  __builtin_amdgcn_global_load_lds(
      (const __attribute__((address_space(1))) unsigned int*)g,
      (__attribute__((address_space(3))) unsigned int*)lds, 16, 0, 0);
}

// ---------------- cast x (fp32 -> bf16, vectorized) ----------------
struct bf16_4 { bf16_t a, b, c, d; };
__global__ void cast_f32_bf16(const float* __restrict__ in, bf16_t* __restrict__ out, int n4) {
  int i = blockIdx.x * blockDim.x + threadIdx.x;
  if (i >= n4) return;
  float4 v = ((const float4*)in)[i];
  bf16_4 r{(bf16_t)v.x, (bf16_t)v.y, (bf16_t)v.z, (bf16_t)v.w};
  ((bf16_4*)out)[i] = r;
}

// ------------- transpose + cast weight: W (K x N) fp32 -> Wt (Np x K) bf16 -------------
// rows n >= N are zero-filled (padding for the GEMM's full-tile staging).
__global__ void transpose_cast(const float* __restrict__ W, bf16_t* __restrict__ Wt,
                               int K, int N, int Np) {
  __shared__ float tile[32][33];
  int k0 = blockIdx.x * 32, n0 = blockIdx.y * 32;
  int tx = threadIdx.x, ty = threadIdx.y;
#pragma unroll
  for (int i = 0; i < 4; ++i) {
    int k = k0 + ty + i * 8, n = n0 + tx;
    float v = (k < K && n < N) ? W[(size_t)k * N + n] : 0.f;
    tile[ty + i * 8][tx] = v;
  }
  __syncthreads();
#pragma unroll
  for (int i = 0; i < 4; ++i) {
    int n = n0 + ty + i * 8, k = k0 + tx;
    if (n < Np && k < K) Wt[(size_t)n * K + k] = (bf16_t)tile[tx][ty + i * 8];
  }
}

// ---------------- GEMM: C(MxN) = A(MxK) * Bt(NxK)^T, bf16 in, fp32 acc ----------------
// MODE 0: store bf16, ldc = row stride
// MODE 1: store fp32, ldc = row stride
// MODE 2: store bf16 head-interleaved: row stride QSTRIDE_, col c -> (c>>7)*192 + (c&127)
template <int MODE>
__global__ __launch_bounds__(256) void gemm_bt(const bf16_t* __restrict__ A,
                                               const bf16_t* __restrict__ Bt,
                                               void* __restrict__ Cv,
                                               int M, int N, int K, int ldc) {
  __shared__ bf16_t As[128 * 32];
  __shared__ bf16_t Bs[128 * 32];
  const int t = threadIdx.x;
  const int w = t >> 6, l = t & 63, l15 = l & 15, lhi = l >> 4;
  const int m0 = blockIdx.y * 128, n0 = blockIdx.x * 128;
  const int wr = (w >> 1) * 64, wc = (w & 1) * 64;

  f32x4 zero = {0.f, 0.f, 0.f, 0.f};
  f32x4 acc[4][4];
#pragma unroll
  for (int m = 0; m < 4; ++m)
#pragma unroll
    for (int n = 0; n < 4; ++n) acc[m][n] = zero;

  const int e0 = t * 8;
  const int r0 = e0 >> 5, c0 = e0 & 31;
  const int e1 = 2048 + t * 8;
  const int r1 = e1 >> 5, c1 = e1 & 31;

  for (int k0 = 0; k0 < K; k0 += 32) {
    gload16(A + (size_t)(m0 + r0) * K + k0 + c0, &As[e0]);
    gload16(A + (size_t)(m0 + r1) * K + k0 + c1, &As[e1]);
    gload16(Bt + (size_t)(n0 + r0) * K + k0 + c0, &Bs[e0]);
    gload16(Bt + (size_t)(n0 + r1) * K + k0 + c1, &Bs[e1]);
    __syncthreads();
    bf16x8 af[4], bfr[4];
#pragma unroll
    for (int m = 0; m < 4; ++m)
      af[m] = *(const bf16x8*)&As[(wr + m * 16 + l15) * 32 + lhi * 8];
#pragma unroll
    for (int n = 0; n < 4; ++n)
      bfr[n] = *(const bf16x8*)&Bs[(wc + n * 16 + l15) * 32 + lhi * 8];
#pragma unroll
    for (int m = 0; m < 4; ++m)
#pragma unroll
      for (int n = 0; n < 4; ++n)
        acc[m][n] = __builtin_amdgcn_mfma_f32_16x16x32_bf16(af[m], bfr[n], acc[m][n], 0, 0, 0);
    __syncthreads();
  }

#pragma unroll
  for (int m = 0; m < 4; ++m) {
#pragma unroll
    for (int n = 0; n < 4; ++n) {
#pragma unroll
      for (int r = 0; r < 4; ++r) {
        int row = m0 + wr + m * 16 + lhi * 4 + r;
        int col = n0 + wc + n * 16 + l15;
        if (col < N) {
          float v = acc[m][n][r];
          if (MODE == 0) {
            ((bf16_t*)Cv)[(size_t)row * ldc + col] = (bf16_t)v;
          } else if (MODE == 1) {
            ((float*)Cv)[(size_t)row * ldc + col] = v;
          } else {
            ((bf16_t*)Cv)[(size_t)row * QSTRIDE_ + (col >> 7) * DQK_ + (col & 127)] = (bf16_t)v;
          }
        }
      }
    }
  }
}

// ---------------- RoPE epilogues ----------------
// q_rope_base: (BT_, 1024) bf16 -> rotate -> Q[:, h*192+128 .. +191]
__global__ void rope_q(const bf16_t* __restrict__ qr, const float* __restrict__ fr,
                       bf16_t* __restrict__ Q) {
  int idx = blockIdx.x * 256 + threadIdx.x;  // BT_*H_*32
  int j = idx & 31;
  int h = (idx >> 5) & 15;
  int row = idx >> 9;
  int tt = row & (T_ - 1);
  float x1 = (float)qr[(size_t)row * 1024 + h * 64 + 2 * j];
  float x2 = (float)qr[(size_t)row * 1024 + h * 64 + 2 * j + 1];
  float c = fr[tt * 64 + 2 * j], s = fr[tt * 64 + 2 * j + 1];
  bf16_t o0 = (bf16_t)(x1 * c - x2 * s);
  bf16_t o1 = (bf16_t)(x1 * s + x2 * c);
  size_t o = (size_t)row * QSTRIDE_ + h * DQK_ + 128 + 2 * j;
  Q[o] = o0;
  Q[o + 1] = o1;
}

// k_rope_base: (BT_, 64) bf16 -> rotate -> broadcast to all 16 heads of K
__global__ void rope_k(const bf16_t* __restrict__ kr, const float* __restrict__ fr,
                       bf16_t* __restrict__ Kb) {
  int idx = blockIdx.x * 256 + threadIdx.x;  // BT_*32
  int j = idx & 31;
  int row = idx >> 5;
  int tt = row & (T_ - 1);
  float x1 = (float)kr[(size_t)row * 64 + 2 * j];
  float x2 = (float)kr[(size_t)row * 64 + 2 * j + 1];
  float c = fr[tt * 64 + 2 * j], s = fr[tt * 64 + 2 * j + 1];
  union { bf16_t h2[2]; unsigned u; } pk;
  pk.h2[0] = (bf16_t)(x1 * c - x2 * s);
  pk.h2[1] = (bf16_t)(x1 * s + x2 * c);
#pragma unroll
  for (int h = 0; h < H_; ++h) {
    *(unsigned*)&Kb[(size_t)row * QSTRIDE_ + h * DQK_ + 128 + 2 * j] = pk.u;
  }
}

// ---------------- causal flash attention ----------------
// grid: (T_/64, B_*H_), block 256 (4 waves x 16 q-rows). d_qk=192, d_v=128.
__global__ __launch_bounds__(256) void flash_attn(const bf16_t* __restrict__ Q,
                                                  const bf16_t* __restrict__ Kb,
                                                  const bf16_t* __restrict__ Vb,
                                                  bf16_t* __restrict__ Ob) {
  constexpr int KLD = 208;  // 192 + 16 pad -> 416B rows (16B aligned, banks spread)
  constexpr int VLD = 80;   // 64 + 16 pad  -> 160B rows
  constexpr int PLD = 80;
  __shared__ bf16_t Ks[64 * KLD];
  __shared__ bf16_t Vt[128 * VLD];
  __shared__ bf16_t Ps[4][16 * PLD];

  const int t = threadIdx.x, w = t >> 6, l = t & 63, l15 = l & 15, lhi = l >> 4;
  const int qt = blockIdx.x, bh = blockIdx.y;
  const int b = bh >> 4, h = bh & 15;
  const int q0 = qt * 64;
  const float scale = 0.07216878364870322f;  // 1/sqrt(192)

  // Q fragments for this wave's 16 rows (row = l15), 6 k-chunks of 32
  bf16x8 qf[6];
  {
    const bf16_t* qrow = Q + ((size_t)(b * T_ + q0 + w * 16 + l15)) * QSTRIDE_ + h * DQK_;
#pragma unroll
    for (int kc = 0; kc < 6; ++kc)
      qf[kc] = *(const bf16x8*)(qrow + kc * 32 + lhi * 8);
  }

  float m_r[4], l_r[4];
  f32x4 zero = {0.f, 0.f, 0.f, 0.f};
  f32x4 accO[8];
#pragma unroll
  for (int r = 0; r < 4; ++r) { m_r[r] = -1e30f; l_r[r] = 0.f; }
#pragma unroll
  for (int n = 0; n < 8; ++n) accO[n] = zero;

  for (int kt = 0; kt <= qt; ++kt) {
    const int k0 = kt * 64;
    __syncthreads();  // previous tile's LDS reads complete
    // stage K tile 64 x 192 (padded rows)
#pragma unroll
    for (int i = 0; i < 6; ++i) {
      int e = (i * 256 + t) * 8;
      int r = e / 192, c = e % 192;
      const bf16_t* src = Kb + ((size_t)(b * T_ + k0 + r)) * QSTRIDE_ + h * DQK_ + c;
      *(bf16x8*)&Ks[r * KLD + c] = *(const bf16x8*)src;
    }
    // stage V tile transposed: Vt[col][krow]
#pragma unroll
    for (int i = 0; i < 4; ++i) {
      int e = (i * 256 + t) * 8;
      int r = e >> 7, c = e & 127;
      const bf16_t* src = Vb + ((size_t)(b * T_ + k0 + r)) * (H_ * DH_) + h * DH_ + c;
      bf16x8 v = *(const bf16x8*)src;
#pragma unroll
      for (int j = 0; j < 8; ++j) Vt[(c + j) * VLD + r] = v[j];
    }
    __syncthreads();

    // scores S[16 x 64] per wave
    f32x4 s[4];
#pragma unroll
    for (int n = 0; n < 4; ++n) s[n] = zero;
#pragma unroll
    for (int kc = 0; kc < 6; ++kc) {
#pragma unroll
      for (int n = 0; n < 4; ++n) {
        bf16x8 kf = *(const bf16x8*)&Ks[(n * 16 + l15) * KLD + kc * 32 + lhi * 8];
        s[n] = __builtin_amdgcn_mfma_f32_16x16x32_bf16(qf[kc], kf, s[n], 0, 0, 0);
      }
    }
    const bool diag = (kt == qt);
#pragma unroll
    for (int n = 0; n < 4; ++n) {
#pragma unroll
      for (int r = 0; r < 4; ++r) {
        float v = s[n][r] * scale;
        if (diag) {
          int qq = w * 16 + lhi * 4 + r;
          int kk = n * 16 + l15;
          if (kk > qq) v = -1e30f;
        }
        s[n][r] = v;
      }
    }
    // wave-parallel row max (rows live in 16-lane groups)
    float mn[4], corr[4];
#pragma unroll
    for (int r = 0; r < 4; ++r) {
      float v = fmaxf(fmaxf(s[0][r], s[1][r]), fmaxf(s[2][r], s[3][r]));
#pragma unroll
      for (int off = 1; off < 16; off <<= 1) v = fmaxf(v, __shfl_xor(v, off, 64));
      mn[r] = fmaxf(m_r[r], v);
      corr[r] = __expf(m_r[r] - mn[r]);
      m_r[r] = mn[r];
    }
    // P = exp(S - m), write per-wave P tile, accumulate row sums
    float rs[4] = {0.f, 0.f, 0.f, 0.f};
#pragma unroll
    for (int n = 0; n < 4; ++n) {
#pragma unroll
      for (int r = 0; r < 4; ++r) {
        float p = __expf(s[n][r] - mn[r]);
        rs[r] += p;
        Ps[w][(lhi * 4 + r) * PLD + n * 16 + l15] = (bf16_t)p;
      }
    }
#pragma unroll
    for (int r = 0; r < 4; ++r) {
      float v = rs[r];
#pragma unroll
      for (int off = 1; off < 16; off <<= 1) v += __shfl_xor(v, off, 64);
      l_r[r] = l_r[r] * corr[r] + v;
    }
#pragma unroll
    for (int n = 0; n < 8; ++n)
#pragma unroll
      for (int r = 0; r < 4; ++r) accO[n][r] *= corr[r];
    // PV: O += P(16x64) @ V(64x128)
#pragma unroll
    for (int kc = 0; kc < 2; ++kc) {
      bf16x8 pf = *(const bf16x8*)&Ps[w][l15 * PLD + kc * 32 + lhi * 8];
#pragma unroll
      for (int n = 0; n < 8; ++n) {
        bf16x8 vf = *(const bf16x8*)&Vt[(n * 16 + l15) * VLD + kc * 32 + lhi * 8];
        accO[n] = __builtin_amdgcn_mfma_f32_16x16x32_bf16(pf, vf, accO[n], 0, 0, 0);
      }
    }
  }

#pragma unroll
  for (int n = 0; n < 8; ++n) {
#pragma unroll
    for (int r = 0; r < 4; ++r) {
      size_t row = (size_t)(b * T_ + q0 + w * 16 + lhi * 4 + r);
      float o = accO[n][r] / l_r[r];
      Ob[row * (H_ * DH_) + h * DH_ + n * 16 + l15] = (bf16_t)o;
    }
  }
}

// ---------------- host ----------------
extern "C" void kernel_launch(void* const* d_in, const int* in_sizes, int n_in,
                              void* d_out, int out_size, void* d_ws, size_t ws_size,
                              hipStream_t stream) {
  (void)in_sizes; (void)n_in; (void)out_size; (void)ws_size;
  const float* x    = (const float*)d_in[0];
  const float* fr   = (const float*)d_in[1];
  // d_in[2] = mask (unused; causal handled analytically)
  const float* Wdq  = (const float*)d_in[3];
  const float* Wuq  = (const float*)d_in[4];
  const float* Wdkv = (const float*)d_in[5];
  const float* Wuk  = (const float*)d_in[6];
  const float* Wuv  = (const float*)d_in[7];
  const float* Wqr  = (const float*)d_in[8];
  const float* Wkr  = (const float*)d_in[9];
  const float* Wo   = (const float*)d_in[10];
  float* out = (float*)d_out;

  char* ws = (char*)d_ws;
  size_t off = 0;
  auto alloc = [&](size_t bytes) -> void* {
    void* p = ws + off;
    off += (bytes + 255) & ~(size_t)255;
    return p;
  };
  bf16_t* x_bf   = (bf16_t*)alloc((size_t)BT_ * DIM_ * 2);
  bf16_t* Wdq_t  = (bf16_t*)alloc((size_t)512 * 2048 * 2);
  bf16_t* Wdkv_t = (bf16_t*)alloc((size_t)512 * 2048 * 2);
  bf16_t* Wqr_t  = (bf16_t*)alloc((size_t)1024 * 512 * 2);
  bf16_t* Wkr_t  = (bf16_t*)alloc((size_t)128 * 2048 * 2);   // padded 64 -> 128 rows
  bf16_t* Wuq_t  = (bf16_t*)alloc((size_t)2048 * 512 * 2);
  bf16_t* Wuk_t  = (bf16_t*)alloc((size_t)2048 * 512 * 2);
  bf16_t* Wuv_t  = (bf16_t*)alloc((size_t)2048 * 512 * 2);
  bf16_t* Wo_t   = (bf16_t*)alloc((size_t)2048 * 2048 * 2);
  bf16_t* q_c    = (bf16_t*)alloc((size_t)BT_ * 512 * 2);
  bf16_t* kv_c   = (bf16_t*)alloc((size_t)BT_ * 512 * 2);
  bf16_t* q_rb   = (bf16_t*)alloc((size_t)BT_ * 1024 * 2);
  bf16_t* k_rb   = (bf16_t*)alloc((size_t)BT_ * 64 * 2);
  bf16_t* Qbuf   = (bf16_t*)alloc((size_t)BT_ * QSTRIDE_ * 2);
  bf16_t* Kbuf   = (bf16_t*)alloc((size_t)BT_ * QSTRIDE_ * 2);
  bf16_t* Vbuf   = (bf16_t*)alloc((size_t)BT_ * 2048 * 2);
  bf16_t* AObuf  = (bf16_t*)alloc((size_t)BT_ * 2048 * 2);

  dim3 tb(32, 8);
  cast_f32_bf16<<<(BT_ * DIM_ / 4 + 255) / 256, 256, 0, stream>>>(x, x_bf, BT_ * DIM_ / 4);
  transpose_cast<<<dim3(64, 16), tb, 0, stream>>>(Wdq,  Wdq_t,  2048, 512, 512);
  transpose_cast<<<dim3(64, 16), tb, 0, stream>>>(Wdkv, Wdkv_t, 2048, 512, 512);
  transpose_cast<<<dim3(16, 32), tb, 0, stream>>>(Wqr,  Wqr_t,  512, 1024, 1024);
  transpose_cast<<<dim3(64, 4),  tb, 0, stream>>>(Wkr,  Wkr_t,  2048, 64, 128);
  transpose_cast<<<dim3(16, 64), tb, 0, stream>>>(Wuq,  Wuq_t,  512, 2048, 2048);
  transpose_cast<<<dim3(16, 64), tb, 0, stream>>>(Wuk,  Wuk_t,  512, 2048, 2048);
  transpose_cast<<<dim3(16, 64), tb, 0, stream>>>(Wuv,  Wuv_t,  512, 2048, 2048);
  transpose_cast<<<dim3(64, 64), tb, 0, stream>>>(Wo,   Wo_t,   2048, 2048, 2048);

  // projections
  gemm_bt<0><<<dim3(4, 32),  256, 0, stream>>>(x_bf, Wdq_t,  q_c,  BT_, 512, 2048, 512);
  gemm_bt<0><<<dim3(4, 32),  256, 0, stream>>>(x_bf, Wdkv_t, kv_c, BT_, 512, 2048, 512);
  gemm_bt<0><<<dim3(8, 32),  256, 0, stream>>>(q_c,  Wqr_t,  q_rb, BT_, 1024, 512, 1024);
  gemm_bt<0><<<dim3(1, 32),  256, 0, stream>>>(x_bf, Wkr_t,  k_rb, BT_, 64, 2048, 64);
  gemm_bt<2><<<dim3(16, 32), 256, 0, stream>>>(q_c,  Wuq_t,  Qbuf, BT_, 2048, 512, 0);
  gemm_bt<2><<<dim3(16, 32), 256, 0, stream>>>(kv_c, Wuk_t,  Kbuf, BT_, 2048, 512, 0);
  gemm_bt<0><<<dim3(16, 32), 256, 0, stream>>>(kv_c, Wuv_t,  Vbuf, BT_, 2048, 512, 2048);

  rope_q<<<(BT_ * H_ * 32) / 256, 256, 0, stream>>>(q_rb, fr, Qbuf);
  rope_k<<<(BT_ * 32) / 256, 256, 0, stream>>>(k_rb, fr, Kbuf);

  flash_attn<<<dim3(T_ / 64, B_ * H_), 256, 0, stream>>>(Qbuf, Kbuf, Vbuf, AObuf);

  // output projection -> fp32
  gemm_bt<1><<<dim3(16, 32), 256, 0, stream>>>(AObuf, Wo_t, out, BT_, 2048, 2048, 2048);
}